// Round 2
// baseline (324.855 us; speedup 1.0000x reference)
//
#include <hip/hip_runtime.h>
#include <math.h>

#define TT 2048
#define LK 769
#define NF 20
#define NS 128
#define NB 18

// ---------------------------------------------------------------------------
// Kernel A: symmetric FIR conv (fwd+bwd averaged == conv with symmetrized
// taps), reflect padding folded into index mirror. One wg per (signal,filter).
// ---------------------------------------------------------------------------
__global__ __launch_bounds__(256) void conv_kernel(const float* __restrict__ x,
                                                   const float* __restrict__ ker,
                                                   float* __restrict__ filt) {
  __shared__ __align__(16) float w[2832];   // padded-signal window spad[384..3200) + zero tail
  __shared__ __align__(16) float hs[776];   // symmetrized filter, zero tail
  __shared__ int sK0, sK1;
  const int tid = threadIdx.x;
  const int blk = blockIdx.x;
  const int n = blk / NF, o = blk % NF;
  if (tid == 0) { sK0 = LK; sK1 = 0; }
  const float* xr = x + n * TT;
  for (int j = tid; j < 2832; j += 256) {
    float v = 0.f;
    if (j < 2816) {
      int m = j - 384;              // spad[j+384] -> original index (j+384)-768
      if (m < 0) m = -m;            // reflect (edge excluded)
      if (m > 2047) m = 4094 - m;
      v = xr[m];
    }
    w[j] = v;
  }
  __syncthreads();
  const float* kr = ker + o * LK;
  for (int k = tid; k < 776; k += 256) {
    float v = 0.f;
    if (k < LK) v = 0.5f * (kr[k] + kr[LK - 1 - k]);
    hs[k] = v;
    if (v != 0.f) { atomicMin(&sK0, k); atomicMax(&sK1, k + 1); }
  }
  __syncthreads();
  int K0 = sK0 & ~3;
  int K1 = (sK1 + 3) & ~3;
  const int t0 = tid * 8;           // 256 threads x 8 outputs = 2048
  float acc[8];
#pragma unroll
  for (int r = 0; r < 8; ++r) acc[r] = 0.f;
  if (K0 < K1) {
    float4 c0 = *(const float4*)&w[t0 + K0];
    float4 c1 = *(const float4*)&w[t0 + K0 + 4];
    for (int k = K0; k < K1; k += 4) {
      float4 c2 = *(const float4*)&w[t0 + k + 8];
      float4 hv = *(const float4*)&hs[k];
      float wr[11] = {c0.x, c0.y, c0.z, c0.w, c1.x, c1.y, c1.z, c1.w,
                      c2.x, c2.y, c2.z};
#pragma unroll
      for (int r = 0; r < 8; ++r) {
        acc[r] = fmaf(hv.x, wr[r],     acc[r]);
        acc[r] = fmaf(hv.y, wr[r + 1], acc[r]);
        acc[r] = fmaf(hv.z, wr[r + 2], acc[r]);
        acc[r] = fmaf(hv.w, wr[r + 3], acc[r]);
      }
      c0 = c1; c1 = c2;
    }
  }
  float* outp = filt + (size_t)blk * TT + t0;
  *(float4*)&outp[0] = make_float4(acc[0], acc[1], acc[2], acc[3]);
  *(float4*)&outp[4] = make_float4(acc[4], acc[5], acc[6], acc[7]);
}

// ---------------------------------------------------------------------------
// Kernel B: circular Hilbert via shared-memory radix-2 FFT (2048), one wg/row.
// Inverse FFT via conjugate trick so only a forward routine is needed.
// ---------------------------------------------------------------------------
__device__ __forceinline__ void fft2048_fwd(float* re, float* im,
                                            const float* twr, const float* twi) {
  const int tid = threadIdx.x;
  for (int t = tid; t < TT; t += 256) {
    int rt = (int)(__brev((unsigned)t) >> 21);
    if (t < rt) {
      float a = re[t], b = re[rt]; re[t] = b; re[rt] = a;
      float c = im[t], d = im[rt]; im[t] = d; im[rt] = c;
    }
  }
  __syncthreads();
  for (int s = 1; s <= 11; ++s) {
    const int half = 1 << (s - 1);
    for (int bf = tid; bf < 1024; bf += 256) {
      const int j = bf & (half - 1);
      const int i0 = ((bf >> (s - 1)) << s) + j;
      const int i1 = i0 + half;
      const float c = twr[half + j], sn = twi[half + j]; // exp(-i*pi*j/half)
      float xr = re[i1], xi = im[i1];
      float tr = fmaf(c, xr, -(sn * xi));
      float ti = fmaf(c, xi, sn * xr);
      float ur = re[i0], ui = im[i0];
      re[i0] = ur + tr; im[i0] = ui + ti;
      re[i1] = ur - tr; im[i1] = ui - ti;
    }
    __syncthreads();
  }
}

__global__ __launch_bounds__(256) void hilbert_kernel(float* __restrict__ filt) {
  __shared__ float re[TT], im[TT];
  __shared__ float twr[TT], twi[TT];
  const int tid = threadIdx.x;
  const int r = blockIdx.x;
  float* row = filt + (size_t)r * TT;
  for (int i = tid; i < TT; i += 256) {
    if (i == 0) { twr[0] = 1.f; twi[0] = 0.f; }
    else {
      int half = 1 << (31 - __clz(i));
      int j = i - half;
      float ang = -3.14159265358979323846f * (float)j / (float)half;
      float s, c;
      sincosf(ang, &s, &c);
      twr[i] = c; twi[i] = s;
    }
    re[i] = row[i];
    im[i] = 0.f;
  }
  __syncthreads();
  fft2048_fwd(re, im, twr, twi);
  // Hilbert mask, then conjugate (to run the inverse as a forward FFT)
  for (int t = tid; t < TT; t += 256) {
    if (t == 0 || t == 1024) { im[t] = -im[t]; }
    else if (t < 1024)       { re[t] *= 2.f; im[t] *= -2.f; }
    else                     { re[t] = 0.f; im[t] = 0.f; }
  }
  __syncthreads();
  fft2048_fwd(re, im, twr, twi);
  // analytic = conj(result)/N
  const bool isPha = (r % NF) < 10;
  const float invN = 1.0f / 2048.0f;
  for (int t = tid; t < TT; t += 256) {
    float ra = re[t], ia = -im[t];
    row[t] = isPha ? atan2f(ia, ra)
                   : sqrtf(fmaf(ra, ra, ia * ia)) * invN;
  }
}

// ---------------------------------------------------------------------------
// Kernel C: binned MI with the reference's RESHAPE-SCRAMBLED pairing.
// The reference reshapes (B*C*S, 10, T) directly to (B, C, 10, S, T), which
// reinterprets flat (s,band) index j = s*10+band as (p', s') = (j/4, j%4).
// So MI output (bc, p', a') averages over s' the MI between
//   phase row j_p = p'*4+s'  (segment j_p/10, pha band j_p%10)
//   amp   row j_a = a'*4+s'  (segment j_a/10, amp band j_a%10)
// One wg per (bc, j_p) = 32*40 blocks; thread = (a', t-slice).
// ---------------------------------------------------------------------------
__global__ __launch_bounds__(256) void mi_kernel(const float* __restrict__ filt,
                                                 float* __restrict__ mi) {
  __shared__ int idx[TT];
  __shared__ float bins[240 * 19];
  __shared__ float cnt[24 * 19];
  __shared__ float asum[10 * 19];
  __shared__ float csum[19];
  const int tid = threadIdx.x;
  const int blk = blockIdx.x;           // bc*40 + jp
  const int bc = blk / 40, jp = blk % 40;
  for (int i = tid; i < 240 * 19; i += 256) bins[i] = 0.f;
  for (int i = tid; i < 24 * 19; i += 256) cnt[i] = 0.f;
  // phase row: segment jp/10, pha band jp%10
  const float* ph = filt + ((size_t)(bc * 4 + jp / 10) * NF + (jp % 10)) * TT;
  for (int t = tid; t < TT; t += 256) {
    float v = ph[t];
    int b = (int)floorf((v + 3.14159274f) / 6.2831855f * 18.0f);
    b = b < 0 ? 0 : (b > 17 ? 17 : b);
    idx[t] = b;
  }
  __syncthreads();
  if (tid < 240) {
    const int a = tid / 24, sl = tid % 24;   // a = a' (output amp index)
    const int ja = (jp & 3) + 4 * a;         // scrambled amp row, same s'
    const float* am = filt + ((size_t)(bc * 4 + ja / 10) * NF + 10 + (ja % 10)) * TT;
    float* bp = &bins[tid * 19];
    if (a == 0) {
      float* cp = &cnt[sl * 19];
      for (int t = sl; t < TT; t += 24) {
        int b = idx[t];
        bp[b] += am[t];
        cp[b] += 1.f;
      }
    } else {
      for (int t = sl; t < TT; t += 24) {
        int b = idx[t];
        bp[b] += am[t];
      }
    }
  }
  __syncthreads();
  if (tid < 180) {
    const int a = tid / 18, b = tid % 18;
    float s = 0.f;
    for (int sl = 0; sl < 24; ++sl) s += bins[(a * 24 + sl) * 19 + b];
    asum[a * 19 + b] = s;
  }
  if (tid >= 192 && tid < 210) {
    const int b = tid - 192;
    float s = 0.f;
    for (int sl = 0; sl < 24; ++sl) s += cnt[sl * 19 + b];
    csum[b] = s;
  }
  __syncthreads();
  if (tid < 10) {
    float tot = 0.f, m[18];
#pragma unroll
    for (int b = 0; b < 18; ++b) {
      float mb = asum[tid * 19 + b] / fmaxf(csum[b], 1.0f);
      m[b] = mb; tot += mb;
    }
    tot = fmaxf(tot, 1e-12f);
    float s = 0.f;
#pragma unroll
    for (int b = 0; b < 18; ++b) {
      float pb = m[b] / tot;
      s += pb * logf(fmaxf(pb, 1e-12f));
    }
    const float LOGN = 2.8903717578961645f; // log(18)
    mi[(size_t)blk * 10 + tid] = (LOGN + s) / LOGN;
  }
}

// ---------------------------------------------------------------------------
// Kernel D: mean over the scrambled s' axis -> out (4,8,10,10)
// ---------------------------------------------------------------------------
__global__ void out_kernel(const float* __restrict__ mi, float* __restrict__ out) {
  int i = blockIdx.x * 256 + threadIdx.x;
  if (i < 3200) {
    int a = i % 10, p = (i / 10) % 10, bc = i / 100;
    float s = 0.f;
    for (int sp = 0; sp < 4; ++sp)
      s += mi[((size_t)(bc * 40 + p * 4 + sp)) * 10 + a];
    out[i] = 0.25f * s;
  }
}

extern "C" void kernel_launch(void* const* d_in, const int* in_sizes, int n_in,
                              void* d_out, int out_size, void* d_ws, size_t ws_size,
                              hipStream_t stream) {
  (void)in_sizes; (void)n_in; (void)out_size; (void)ws_size;
  const float* x = (const float*)d_in[0];     // (4,8,4,2048) fp32
  const float* ker = (const float*)d_in[1];   // (20,769) fp32
  float* out = (float*)d_out;                 // 3200 fp32
  float* filt = (float*)d_ws;                 // 128*20*2048 fp32 (~21 MB)
  float* mi = filt + (size_t)NS * NF * TT;    // 12800 fp32

  conv_kernel<<<NS * NF, 256, 0, stream>>>(x, ker, filt);
  hilbert_kernel<<<NS * NF, 256, 0, stream>>>(filt);
  mi_kernel<<<32 * 40, 256, 0, stream>>>(filt, mi);
  out_kernel<<<(3200 + 255) / 256, 256, 0, stream>>>(mi, out);
}

// Round 3
// 320.669 us; speedup vs baseline: 1.0131x; 1.0131x over previous
//
#include <hip/hip_runtime.h>
#include <math.h>

#define TT 2048
#define LK 769
#define NF 20
#define NS 128
#define NB 18

// ---------------------------------------------------------------------------
// Kernel A: symmetric FIR conv (fwd+bwd averaged == conv with symmetrized
// taps), reflect padding folded into index mirror. One wg per (signal,filter).
// Lane -> two groups of 4 contiguous outputs (4*tid, 1024+4*tid) so every
// LDS b128 read of w is 64 lanes x 16B contiguous = conflict-free.
// ---------------------------------------------------------------------------
__global__ __launch_bounds__(256) void conv_kernel(const float* __restrict__ x,
                                                   const float* __restrict__ ker,
                                                   float* __restrict__ filt) {
  __shared__ __align__(16) float w[2832];   // padded-signal window spad[384..3200) + zero tail
  __shared__ __align__(16) float hs[776];   // symmetrized filter, zero tail
  __shared__ int sK0, sK1;
  const int tid = threadIdx.x;
  const int blk = blockIdx.x;
  const int n = blk / NF, o = blk % NF;
  if (tid == 0) { sK0 = LK; sK1 = 0; }
  const float* xr = x + n * TT;
  for (int j = tid; j < 2832; j += 256) {
    float v = 0.f;
    if (j < 2816) {
      int m = j - 384;              // spad[j+384] -> original index (j+384)-768
      if (m < 0) m = -m;            // reflect (edge excluded)
      if (m > 2047) m = 4094 - m;
      v = xr[m];
    }
    w[j] = v;
  }
  __syncthreads();
  const float* kr = ker + o * LK;
  for (int k = tid; k < 776; k += 256) {
    float v = 0.f;
    if (k < LK) v = 0.5f * (kr[k] + kr[LK - 1 - k]);
    hs[k] = v;
    if (v != 0.f) { atomicMin(&sK0, k); atomicMax(&sK1, k + 1); }
  }
  __syncthreads();
  const int K0 = sK0 & ~3;
  const int K1 = (sK1 + 3) & ~3;
  const int bA = 4 * tid;           // group A outputs [bA, bA+4)
  const int bB = 1024 + 4 * tid;    // group B outputs [bB, bB+4)
  float accA[4], accB[4];
#pragma unroll
  for (int r = 0; r < 4; ++r) { accA[r] = 0.f; accB[r] = 0.f; }
  if (K0 < K1) {
    float4 a0 = *(const float4*)&w[bA + K0];
    float4 a1 = *(const float4*)&w[bA + K0 + 4];
    float4 b0 = *(const float4*)&w[bB + K0];
    float4 b1 = *(const float4*)&w[bB + K0 + 4];
    for (int k = K0; k < K1; k += 4) {
      float4 a2 = *(const float4*)&w[bA + k + 8];
      float4 b2 = *(const float4*)&w[bB + k + 8];
      float4 hv = *(const float4*)&hs[k];
      float wa[7] = {a0.x, a0.y, a0.z, a0.w, a1.x, a1.y, a1.z};
      float wb[7] = {b0.x, b0.y, b0.z, b0.w, b1.x, b1.y, b1.z};
#pragma unroll
      for (int r = 0; r < 4; ++r) {
        accA[r] = fmaf(hv.x, wa[r],     accA[r]);
        accA[r] = fmaf(hv.y, wa[r + 1], accA[r]);
        accA[r] = fmaf(hv.z, wa[r + 2], accA[r]);
        accA[r] = fmaf(hv.w, wa[r + 3], accA[r]);
        accB[r] = fmaf(hv.x, wb[r],     accB[r]);
        accB[r] = fmaf(hv.y, wb[r + 1], accB[r]);
        accB[r] = fmaf(hv.z, wb[r + 2], accB[r]);
        accB[r] = fmaf(hv.w, wb[r + 3], accB[r]);
      }
      a0 = a1; a1 = a2;
      b0 = b1; b1 = b2;
    }
  }
  float* outp = filt + (size_t)blk * TT;
  *(float4*)&outp[bA] = make_float4(accA[0], accA[1], accA[2], accA[3]);
  *(float4*)&outp[bB] = make_float4(accB[0], accB[1], accB[2], accB[3]);
}

// ---------------------------------------------------------------------------
// Kernel B: circular Hilbert via shared-memory radix-2 FFT (2048), one wg/row.
// Inverse FFT via conjugate trick so only a forward routine is needed.
// ---------------------------------------------------------------------------
__device__ __forceinline__ void fft2048_fwd(float* re, float* im,
                                            const float* twr, const float* twi) {
  const int tid = threadIdx.x;
  for (int t = tid; t < TT; t += 256) {
    int rt = (int)(__brev((unsigned)t) >> 21);
    if (t < rt) {
      float a = re[t], b = re[rt]; re[t] = b; re[rt] = a;
      float c = im[t], d = im[rt]; im[t] = d; im[rt] = c;
    }
  }
  __syncthreads();
  for (int s = 1; s <= 11; ++s) {
    const int half = 1 << (s - 1);
    for (int bf = tid; bf < 1024; bf += 256) {
      const int j = bf & (half - 1);
      const int i0 = ((bf >> (s - 1)) << s) + j;
      const int i1 = i0 + half;
      const float c = twr[half + j], sn = twi[half + j]; // exp(-i*pi*j/half)
      float xr = re[i1], xi = im[i1];
      float tr = fmaf(c, xr, -(sn * xi));
      float ti = fmaf(c, xi, sn * xr);
      float ur = re[i0], ui = im[i0];
      re[i0] = ur + tr; im[i0] = ui + ti;
      re[i1] = ur - tr; im[i1] = ui - ti;
    }
    __syncthreads();
  }
}

__global__ __launch_bounds__(256) void hilbert_kernel(float* __restrict__ filt) {
  __shared__ float re[TT], im[TT];
  __shared__ float twr[TT], twi[TT];
  const int tid = threadIdx.x;
  const int r = blockIdx.x;
  float* row = filt + (size_t)r * TT;
  for (int i = tid; i < TT; i += 256) {
    if (i == 0) { twr[0] = 1.f; twi[0] = 0.f; }
    else {
      int half = 1 << (31 - __clz(i));
      int j = i - half;
      float ang = -3.14159265358979323846f * (float)j / (float)half;
      float s, c;
      sincosf(ang, &s, &c);
      twr[i] = c; twi[i] = s;
    }
    re[i] = row[i];
    im[i] = 0.f;
  }
  __syncthreads();
  fft2048_fwd(re, im, twr, twi);
  // Hilbert mask, then conjugate (to run the inverse as a forward FFT)
  for (int t = tid; t < TT; t += 256) {
    if (t == 0 || t == 1024) { im[t] = -im[t]; }
    else if (t < 1024)       { re[t] *= 2.f; im[t] *= -2.f; }
    else                     { re[t] = 0.f; im[t] = 0.f; }
  }
  __syncthreads();
  fft2048_fwd(re, im, twr, twi);
  // analytic = conj(result)/N
  const bool isPha = (r % NF) < 10;
  const float invN = 1.0f / 2048.0f;
  for (int t = tid; t < TT; t += 256) {
    float ra = re[t], ia = -im[t];
    row[t] = isPha ? atan2f(ia, ra)
                   : sqrtf(fmaf(ra, ra, ia * ia)) * invN;
  }
}

// ---------------------------------------------------------------------------
// Kernel C: binned MI with the reference's RESHAPE-SCRAMBLED pairing.
// The reference reshapes (B*C*S, 10, T) directly to (B, C, 10, S, T), which
// reinterprets flat (s,band) index j = s*10+band as (p', s') = (j/4, j%4).
// So MI output (bc, p', a') averages over s' the MI between
//   phase row j_p = p'*4+s'  (segment j_p/10, pha band j_p%10)
//   amp   row j_a = a'*4+s'  (segment j_a/10, amp band j_a%10)
// One wg per (bc, j_p) = 32*40 blocks; thread = (a', t-slice).
// ---------------------------------------------------------------------------
__global__ __launch_bounds__(256) void mi_kernel(const float* __restrict__ filt,
                                                 float* __restrict__ mi) {
  __shared__ int idx[TT];
  __shared__ float bins[240 * 19];
  __shared__ float cnt[24 * 19];
  __shared__ float asum[10 * 19];
  __shared__ float csum[19];
  const int tid = threadIdx.x;
  const int blk = blockIdx.x;           // bc*40 + jp
  const int bc = blk / 40, jp = blk % 40;
  for (int i = tid; i < 240 * 19; i += 256) bins[i] = 0.f;
  for (int i = tid; i < 24 * 19; i += 256) cnt[i] = 0.f;
  // phase row: segment jp/10, pha band jp%10
  const float* ph = filt + ((size_t)(bc * 4 + jp / 10) * NF + (jp % 10)) * TT;
  for (int t = tid; t < TT; t += 256) {
    float v = ph[t];
    int b = (int)floorf((v + 3.14159274f) / 6.2831855f * 18.0f);
    b = b < 0 ? 0 : (b > 17 ? 17 : b);
    idx[t] = b;
  }
  __syncthreads();
  if (tid < 240) {
    const int a = tid / 24, sl = tid % 24;   // a = a' (output amp index)
    const int ja = (jp & 3) + 4 * a;         // scrambled amp row, same s'
    const float* am = filt + ((size_t)(bc * 4 + ja / 10) * NF + 10 + (ja % 10)) * TT;
    float* bp = &bins[tid * 19];
    if (a == 0) {
      float* cp = &cnt[sl * 19];
      for (int t = sl; t < TT; t += 24) {
        int b = idx[t];
        bp[b] += am[t];
        cp[b] += 1.f;
      }
    } else {
      for (int t = sl; t < TT; t += 24) {
        int b = idx[t];
        bp[b] += am[t];
      }
    }
  }
  __syncthreads();
  if (tid < 180) {
    const int a = tid / 18, b = tid % 18;
    float s = 0.f;
    for (int sl = 0; sl < 24; ++sl) s += bins[(a * 24 + sl) * 19 + b];
    asum[a * 19 + b] = s;
  }
  if (tid >= 192 && tid < 210) {
    const int b = tid - 192;
    float s = 0.f;
    for (int sl = 0; sl < 24; ++sl) s += cnt[sl * 19 + b];
    csum[b] = s;
  }
  __syncthreads();
  if (tid < 10) {
    float tot = 0.f, m[18];
#pragma unroll
    for (int b = 0; b < 18; ++b) {
      float mb = asum[tid * 19 + b] / fmaxf(csum[b], 1.0f);
      m[b] = mb; tot += mb;
    }
    tot = fmaxf(tot, 1e-12f);
    float s = 0.f;
#pragma unroll
    for (int b = 0; b < 18; ++b) {
      float pb = m[b] / tot;
      s += pb * logf(fmaxf(pb, 1e-12f));
    }
    const float LOGN = 2.8903717578961645f; // log(18)
    mi[(size_t)blk * 10 + tid] = (LOGN + s) / LOGN;
  }
}

// ---------------------------------------------------------------------------
// Kernel D: mean over the scrambled s' axis -> out (4,8,10,10)
// ---------------------------------------------------------------------------
__global__ void out_kernel(const float* __restrict__ mi, float* __restrict__ out) {
  int i = blockIdx.x * 256 + threadIdx.x;
  if (i < 3200) {
    int a = i % 10, p = (i / 10) % 10, bc = i / 100;
    float s = 0.f;
    for (int sp = 0; sp < 4; ++sp)
      s += mi[((size_t)(bc * 40 + p * 4 + sp)) * 10 + a];
    out[i] = 0.25f * s;
  }
}

extern "C" void kernel_launch(void* const* d_in, const int* in_sizes, int n_in,
                              void* d_out, int out_size, void* d_ws, size_t ws_size,
                              hipStream_t stream) {
  (void)in_sizes; (void)n_in; (void)out_size; (void)ws_size;
  const float* x = (const float*)d_in[0];     // (4,8,4,2048) fp32
  const float* ker = (const float*)d_in[1];   // (20,769) fp32
  float* out = (float*)d_out;                 // 3200 fp32
  float* filt = (float*)d_ws;                 // 128*20*2048 fp32 (~21 MB)
  float* mi = filt + (size_t)NS * NF * TT;    // 12800 fp32

  conv_kernel<<<NS * NF, 256, 0, stream>>>(x, ker, filt);
  hilbert_kernel<<<NS * NF, 256, 0, stream>>>(filt);
  mi_kernel<<<32 * 40, 256, 0, stream>>>(filt, mi);
  out_kernel<<<(3200 + 255) / 256, 256, 0, stream>>>(mi, out);
}

// Round 4
// 251.061 us; speedup vs baseline: 1.2939x; 1.2773x over previous
//
#include <hip/hip_runtime.h>
#include <math.h>

#define TT 2048
#define LK 769
#define NF 20
#define NS 128
#define NB 18

// ---------------------------------------------------------------------------
// Kernel A: symmetric FIR conv (fwd+bwd averaged == conv with symmetrized
// taps), reflect padding folded into index mirror.
// One wg per (signal, filter-PAIR): pha band p + amp band (9-p) share the
// same LDS signal window (2x FMA per LDS byte). Tap ranges found with a
// shuffle reduction (no LDS atomics). Blocks ordered longest-pair-first.
// Per-output tap order identical to the single-filter version (bit-exact).
// ---------------------------------------------------------------------------
__global__ __launch_bounds__(256) void conv_kernel(const float* __restrict__ x,
                                                   const float* __restrict__ ker,
                                                   float* __restrict__ filt) {
  __shared__ __align__(16) float w[2832];   // spad[384..3200) + zero tail
  __shared__ __align__(16) float hs1[784];  // symmetrized pha filter
  __shared__ __align__(16) float hs2[784];  // symmetrized amp filter
  __shared__ int red[4][4];
  const int tid = threadIdx.x;
  const int ord = blockIdx.x;
  const int p = ord / NS;                   // 0..9, longest pair first
  const int n = ord % NS;
  const int o1 = p;                          // pha band
  const int o2 = 10 + (9 - p);               // amp band (short with long)
  const float* xr = x + n * TT;
  for (int j = tid; j < 2832; j += 256) {
    float v = 0.f;
    if (j < 2816) {
      int m = j - 384;              // spad[j+384] -> original index (j+384)-768
      if (m < 0) m = -m;            // reflect (edge excluded)
      if (m > 2047) m = 4094 - m;
      v = xr[m];
    }
    w[j] = v;
  }
  const float* kr1 = ker + o1 * LK;
  const float* kr2 = ker + o2 * LK;
  int k0 = 784, k1 = 0, m0 = 784, m1 = 0;
  for (int k = tid; k < 784; k += 256) {
    float v1 = 0.f, v2 = 0.f;
    if (k < LK) {
      v1 = 0.5f * (kr1[k] + kr1[LK - 1 - k]);
      v2 = 0.5f * (kr2[k] + kr2[LK - 1 - k]);
    }
    hs1[k] = v1;
    hs2[k] = v2;
    if (v1 != 0.f) { k0 = min(k0, k); k1 = max(k1, k + 1); }
    if (v2 != 0.f) { m0 = min(m0, k); m1 = max(m1, k + 1); }
  }
  // wave-level reduce (no atomics), then cross-wave combine via tiny LDS
#pragma unroll
  for (int off = 32; off > 0; off >>= 1) {
    k0 = min(k0, __shfl_down(k0, off));
    k1 = max(k1, __shfl_down(k1, off));
    m0 = min(m0, __shfl_down(m0, off));
    m1 = max(m1, __shfl_down(m1, off));
  }
  const int wid = tid >> 6;
  if ((tid & 63) == 0) { red[wid][0] = k0; red[wid][1] = k1; red[wid][2] = m0; red[wid][3] = m1; }
  __syncthreads();
  k0 = min(min(red[0][0], red[1][0]), min(red[2][0], red[3][0]));
  k1 = max(max(red[0][1], red[1][1]), max(red[2][1], red[3][1]));
  m0 = min(min(red[0][2], red[1][2]), min(red[2][2], red[3][2]));
  m1 = max(max(red[0][3], red[1][3]), max(red[2][3], red[3][3]));
  const int A0 = __builtin_amdgcn_readfirstlane(k0 & ~3);
  const int A1 = __builtin_amdgcn_readfirstlane((k1 + 3) & ~3);
  const int B0 = __builtin_amdgcn_readfirstlane(m0 & ~3);
  const int B1 = __builtin_amdgcn_readfirstlane((m1 + 3) & ~3);
  const int U0 = min(A0, B0);
  const int U1 = max(A1, B1);

  const int bA = 4 * tid;           // group A outputs [bA, bA+4)
  const int bB = 1024 + 4 * tid;    // group B outputs [bB, bB+4)
  float acc1A[4], acc1B[4], acc2A[4], acc2B[4];
#pragma unroll
  for (int r = 0; r < 4; ++r) { acc1A[r] = 0.f; acc1B[r] = 0.f; acc2A[r] = 0.f; acc2B[r] = 0.f; }
  if (U0 < U1) {
    float4 a0 = *(const float4*)&w[bA + U0];
    float4 a1 = *(const float4*)&w[bA + U0 + 4];
    float4 b0 = *(const float4*)&w[bB + U0];
    float4 b1 = *(const float4*)&w[bB + U0 + 4];
    float4 hv1 = *(const float4*)&hs1[U0];
    float4 hv2 = *(const float4*)&hs2[U0];
    for (int k = U0; k < U1; k += 4) {
      float4 hv1n = *(const float4*)&hs1[k + 4];   // prefetch next taps
      float4 hv2n = *(const float4*)&hs2[k + 4];
      float4 a2 = *(const float4*)&w[bA + k + 8];  // prefetch next window
      float4 b2 = *(const float4*)&w[bB + k + 8];
      float wa[7] = {a0.x, a0.y, a0.z, a0.w, a1.x, a1.y, a1.z};
      float wb[7] = {b0.x, b0.y, b0.z, b0.w, b1.x, b1.y, b1.z};
      if (k >= A0 && k < A1) {
#pragma unroll
        for (int r = 0; r < 4; ++r) {
          acc1A[r] = fmaf(hv1.x, wa[r],     acc1A[r]);
          acc1A[r] = fmaf(hv1.y, wa[r + 1], acc1A[r]);
          acc1A[r] = fmaf(hv1.z, wa[r + 2], acc1A[r]);
          acc1A[r] = fmaf(hv1.w, wa[r + 3], acc1A[r]);
          acc1B[r] = fmaf(hv1.x, wb[r],     acc1B[r]);
          acc1B[r] = fmaf(hv1.y, wb[r + 1], acc1B[r]);
          acc1B[r] = fmaf(hv1.z, wb[r + 2], acc1B[r]);
          acc1B[r] = fmaf(hv1.w, wb[r + 3], acc1B[r]);
        }
      }
      if (k >= B0 && k < B1) {
#pragma unroll
        for (int r = 0; r < 4; ++r) {
          acc2A[r] = fmaf(hv2.x, wa[r],     acc2A[r]);
          acc2A[r] = fmaf(hv2.y, wa[r + 1], acc2A[r]);
          acc2A[r] = fmaf(hv2.z, wa[r + 2], acc2A[r]);
          acc2A[r] = fmaf(hv2.w, wa[r + 3], acc2A[r]);
          acc2B[r] = fmaf(hv2.x, wb[r],     acc2B[r]);
          acc2B[r] = fmaf(hv2.y, wb[r + 1], acc2B[r]);
          acc2B[r] = fmaf(hv2.z, wb[r + 2], acc2B[r]);
          acc2B[r] = fmaf(hv2.w, wb[r + 3], acc2B[r]);
        }
      }
      a0 = a1; a1 = a2;
      b0 = b1; b1 = b2;
      hv1 = hv1n; hv2 = hv2n;
    }
  }
  float* out1 = filt + ((size_t)n * NF + o1) * TT;
  float* out2 = filt + ((size_t)n * NF + o2) * TT;
  *(float4*)&out1[bA] = make_float4(acc1A[0], acc1A[1], acc1A[2], acc1A[3]);
  *(float4*)&out1[bB] = make_float4(acc1B[0], acc1B[1], acc1B[2], acc1B[3]);
  *(float4*)&out2[bA] = make_float4(acc2A[0], acc2A[1], acc2A[2], acc2A[3]);
  *(float4*)&out2[bB] = make_float4(acc2B[0], acc2B[1], acc2B[2], acc2B[3]);
}

// ---------------------------------------------------------------------------
// Kernel B: circular Hilbert via shared-memory radix-2 FFT (2048), one wg/row.
// Inverse FFT via conjugate trick so only a forward routine is needed.
// ---------------------------------------------------------------------------
__device__ __forceinline__ void fft2048_fwd(float* re, float* im,
                                            const float* twr, const float* twi) {
  const int tid = threadIdx.x;
  for (int t = tid; t < TT; t += 256) {
    int rt = (int)(__brev((unsigned)t) >> 21);
    if (t < rt) {
      float a = re[t], b = re[rt]; re[t] = b; re[rt] = a;
      float c = im[t], d = im[rt]; im[t] = d; im[rt] = c;
    }
  }
  __syncthreads();
  for (int s = 1; s <= 11; ++s) {
    const int half = 1 << (s - 1);
    for (int bf = tid; bf < 1024; bf += 256) {
      const int j = bf & (half - 1);
      const int i0 = ((bf >> (s - 1)) << s) + j;
      const int i1 = i0 + half;
      const float c = twr[half + j], sn = twi[half + j]; // exp(-i*pi*j/half)
      float xr = re[i1], xi = im[i1];
      float tr = fmaf(c, xr, -(sn * xi));
      float ti = fmaf(c, xi, sn * xr);
      float ur = re[i0], ui = im[i0];
      re[i0] = ur + tr; im[i0] = ui + ti;
      re[i1] = ur - tr; im[i1] = ui - ti;
    }
    __syncthreads();
  }
}

__global__ __launch_bounds__(256) void hilbert_kernel(float* __restrict__ filt) {
  __shared__ float re[TT], im[TT];
  __shared__ float twr[TT], twi[TT];
  const int tid = threadIdx.x;
  const int r = blockIdx.x;
  float* row = filt + (size_t)r * TT;
  for (int i = tid; i < TT; i += 256) {
    if (i == 0) { twr[0] = 1.f; twi[0] = 0.f; }
    else {
      int half = 1 << (31 - __clz(i));
      int j = i - half;
      float ang = -3.14159265358979323846f * (float)j / (float)half;
      float s, c;
      sincosf(ang, &s, &c);
      twr[i] = c; twi[i] = s;
    }
    re[i] = row[i];
    im[i] = 0.f;
  }
  __syncthreads();
  fft2048_fwd(re, im, twr, twi);
  // Hilbert mask, then conjugate (to run the inverse as a forward FFT)
  for (int t = tid; t < TT; t += 256) {
    if (t == 0 || t == 1024) { im[t] = -im[t]; }
    else if (t < 1024)       { re[t] *= 2.f; im[t] *= -2.f; }
    else                     { re[t] = 0.f; im[t] = 0.f; }
  }
  __syncthreads();
  fft2048_fwd(re, im, twr, twi);
  // analytic = conj(result)/N
  const bool isPha = (r % NF) < 10;
  const float invN = 1.0f / 2048.0f;
  for (int t = tid; t < TT; t += 256) {
    float ra = re[t], ia = -im[t];
    row[t] = isPha ? atan2f(ia, ra)
                   : sqrtf(fmaf(ra, ra, ia * ia)) * invN;
  }
}

// ---------------------------------------------------------------------------
// Kernel C: binned MI with the reference's RESHAPE-SCRAMBLED pairing.
// The reference reshapes (B*C*S, 10, T) directly to (B, C, 10, S, T), which
// reinterprets flat (s,band) index j = s*10+band as (p', s') = (j/4, j%4).
// So MI output (bc, p', a') averages over s' the MI between
//   phase row j_p = p'*4+s'  (segment j_p/10, pha band j_p%10)
//   amp   row j_a = a'*4+s'  (segment j_a/10, amp band j_a%10)
// One wg per (bc, j_p) = 32*40 blocks; thread = (a', t-slice).
// ---------------------------------------------------------------------------
__global__ __launch_bounds__(256) void mi_kernel(const float* __restrict__ filt,
                                                 float* __restrict__ mi) {
  __shared__ int idx[TT];
  __shared__ float bins[240 * 19];
  __shared__ float cnt[24 * 19];
  __shared__ float asum[10 * 19];
  __shared__ float csum[19];
  const int tid = threadIdx.x;
  const int blk = blockIdx.x;           // bc*40 + jp
  const int bc = blk / 40, jp = blk % 40;
  for (int i = tid; i < 240 * 19; i += 256) bins[i] = 0.f;
  for (int i = tid; i < 24 * 19; i += 256) cnt[i] = 0.f;
  // phase row: segment jp/10, pha band jp%10
  const float* ph = filt + ((size_t)(bc * 4 + jp / 10) * NF + (jp % 10)) * TT;
  for (int t = tid; t < TT; t += 256) {
    float v = ph[t];
    int b = (int)floorf((v + 3.14159274f) / 6.2831855f * 18.0f);
    b = b < 0 ? 0 : (b > 17 ? 17 : b);
    idx[t] = b;
  }
  __syncthreads();
  if (tid < 240) {
    const int a = tid / 24, sl = tid % 24;   // a = a' (output amp index)
    const int ja = (jp & 3) + 4 * a;         // scrambled amp row, same s'
    const float* am = filt + ((size_t)(bc * 4 + ja / 10) * NF + 10 + (ja % 10)) * TT;
    float* bp = &bins[tid * 19];
    if (a == 0) {
      float* cp = &cnt[sl * 19];
      for (int t = sl; t < TT; t += 24) {
        int b = idx[t];
        bp[b] += am[t];
        cp[b] += 1.f;
      }
    } else {
      for (int t = sl; t < TT; t += 24) {
        int b = idx[t];
        bp[b] += am[t];
      }
    }
  }
  __syncthreads();
  if (tid < 180) {
    const int a = tid / 18, b = tid % 18;
    float s = 0.f;
    for (int sl = 0; sl < 24; ++sl) s += bins[(a * 24 + sl) * 19 + b];
    asum[a * 19 + b] = s;
  }
  if (tid >= 192 && tid < 210) {
    const int b = tid - 192;
    float s = 0.f;
    for (int sl = 0; sl < 24; ++sl) s += cnt[sl * 19 + b];
    csum[b] = s;
  }
  __syncthreads();
  if (tid < 10) {
    float tot = 0.f, m[18];
#pragma unroll
    for (int b = 0; b < 18; ++b) {
      float mb = asum[tid * 19 + b] / fmaxf(csum[b], 1.0f);
      m[b] = mb; tot += mb;
    }
    tot = fmaxf(tot, 1e-12f);
    float s = 0.f;
#pragma unroll
    for (int b = 0; b < 18; ++b) {
      float pb = m[b] / tot;
      s += pb * logf(fmaxf(pb, 1e-12f));
    }
    const float LOGN = 2.8903717578961645f; // log(18)
    mi[(size_t)blk * 10 + tid] = (LOGN + s) / LOGN;
  }
}

// ---------------------------------------------------------------------------
// Kernel D: mean over the scrambled s' axis -> out (4,8,10,10)
// ---------------------------------------------------------------------------
__global__ void out_kernel(const float* __restrict__ mi, float* __restrict__ out) {
  int i = blockIdx.x * 256 + threadIdx.x;
  if (i < 3200) {
    int a = i % 10, p = (i / 10) % 10, bc = i / 100;
    float s = 0.f;
    for (int sp = 0; sp < 4; ++sp)
      s += mi[((size_t)(bc * 40 + p * 4 + sp)) * 10 + a];
    out[i] = 0.25f * s;
  }
}

extern "C" void kernel_launch(void* const* d_in, const int* in_sizes, int n_in,
                              void* d_out, int out_size, void* d_ws, size_t ws_size,
                              hipStream_t stream) {
  (void)in_sizes; (void)n_in; (void)out_size; (void)ws_size;
  const float* x = (const float*)d_in[0];     // (4,8,4,2048) fp32
  const float* ker = (const float*)d_in[1];   // (20,769) fp32
  float* out = (float*)d_out;                 // 3200 fp32
  float* filt = (float*)d_ws;                 // 128*20*2048 fp32 (~21 MB)
  float* mi = filt + (size_t)NS * NF * TT;    // 12800 fp32

  conv_kernel<<<NS * 10, 256, 0, stream>>>(x, ker, filt);
  hilbert_kernel<<<NS * NF, 256, 0, stream>>>(filt);
  mi_kernel<<<32 * 40, 256, 0, stream>>>(filt, mi);
  out_kernel<<<(3200 + 255) / 256, 256, 0, stream>>>(mi, out);
}

// Round 5
// 233.518 us; speedup vs baseline: 1.3911x; 1.0751x over previous
//
#include <hip/hip_runtime.h>
#include <math.h>

#define TT 2048
#define LK 769
#define NF 20
#define NS 128
#define NB 18

// ---------------------------------------------------------------------------
// Kernel A: symmetric FIR conv (fwd+bwd averaged == conv with symmetrized
// taps), reflect padding folded into index mirror.
// One wg per (signal, filter-PAIR): pha band p + amp band (9-p) share the
// same LDS signal window (2x FMA per LDS byte). Tap ranges found with a
// shuffle reduction (no LDS atomics). Blocks ordered longest-pair-first.
// ---------------------------------------------------------------------------
__global__ __launch_bounds__(256) void conv_kernel(const float* __restrict__ x,
                                                   const float* __restrict__ ker,
                                                   float* __restrict__ filt) {
  __shared__ __align__(16) float w[2832];   // spad[384..3200) + zero tail
  __shared__ __align__(16) float hs1[784];  // symmetrized pha filter
  __shared__ __align__(16) float hs2[784];  // symmetrized amp filter
  __shared__ int red[4][4];
  const int tid = threadIdx.x;
  const int ord = blockIdx.x;
  const int p = ord / NS;                   // 0..9, longest pair first
  const int n = ord % NS;
  const int o1 = p;                          // pha band
  const int o2 = 10 + (9 - p);               // amp band (short with long)
  const float* xr = x + n * TT;
  for (int j = tid; j < 2832; j += 256) {
    float v = 0.f;
    if (j < 2816) {
      int m = j - 384;              // spad[j+384] -> original index (j+384)-768
      if (m < 0) m = -m;            // reflect (edge excluded)
      if (m > 2047) m = 4094 - m;
      v = xr[m];
    }
    w[j] = v;
  }
  const float* kr1 = ker + o1 * LK;
  const float* kr2 = ker + o2 * LK;
  int k0 = 784, k1 = 0, m0 = 784, m1 = 0;
  for (int k = tid; k < 784; k += 256) {
    float v1 = 0.f, v2 = 0.f;
    if (k < LK) {
      v1 = 0.5f * (kr1[k] + kr1[LK - 1 - k]);
      v2 = 0.5f * (kr2[k] + kr2[LK - 1 - k]);
    }
    hs1[k] = v1;
    hs2[k] = v2;
    if (v1 != 0.f) { k0 = min(k0, k); k1 = max(k1, k + 1); }
    if (v2 != 0.f) { m0 = min(m0, k); m1 = max(m1, k + 1); }
  }
#pragma unroll
  for (int off = 32; off > 0; off >>= 1) {
    k0 = min(k0, __shfl_down(k0, off));
    k1 = max(k1, __shfl_down(k1, off));
    m0 = min(m0, __shfl_down(m0, off));
    m1 = max(m1, __shfl_down(m1, off));
  }
  const int wid = tid >> 6;
  if ((tid & 63) == 0) { red[wid][0] = k0; red[wid][1] = k1; red[wid][2] = m0; red[wid][3] = m1; }
  __syncthreads();
  k0 = min(min(red[0][0], red[1][0]), min(red[2][0], red[3][0]));
  k1 = max(max(red[0][1], red[1][1]), max(red[2][1], red[3][1]));
  m0 = min(min(red[0][2], red[1][2]), min(red[2][2], red[3][2]));
  m1 = max(max(red[0][3], red[1][3]), max(red[2][3], red[3][3]));
  const int A0 = __builtin_amdgcn_readfirstlane(k0 & ~3);
  const int A1 = __builtin_amdgcn_readfirstlane((k1 + 3) & ~3);
  const int B0 = __builtin_amdgcn_readfirstlane(m0 & ~3);
  const int B1 = __builtin_amdgcn_readfirstlane((m1 + 3) & ~3);
  const int U0 = min(A0, B0);
  const int U1 = max(A1, B1);

  const int bA = 4 * tid;           // group A outputs [bA, bA+4)
  const int bB = 1024 + 4 * tid;    // group B outputs [bB, bB+4)
  float acc1A[4], acc1B[4], acc2A[4], acc2B[4];
#pragma unroll
  for (int r = 0; r < 4; ++r) { acc1A[r] = 0.f; acc1B[r] = 0.f; acc2A[r] = 0.f; acc2B[r] = 0.f; }
  if (U0 < U1) {
    float4 a0 = *(const float4*)&w[bA + U0];
    float4 a1 = *(const float4*)&w[bA + U0 + 4];
    float4 b0 = *(const float4*)&w[bB + U0];
    float4 b1 = *(const float4*)&w[bB + U0 + 4];
    float4 hv1 = *(const float4*)&hs1[U0];
    float4 hv2 = *(const float4*)&hs2[U0];
    for (int k = U0; k < U1; k += 4) {
      float4 hv1n = *(const float4*)&hs1[k + 4];   // prefetch next taps
      float4 hv2n = *(const float4*)&hs2[k + 4];
      float4 a2 = *(const float4*)&w[bA + k + 8];  // prefetch next window
      float4 b2 = *(const float4*)&w[bB + k + 8];
      float wa[7] = {a0.x, a0.y, a0.z, a0.w, a1.x, a1.y, a1.z};
      float wb[7] = {b0.x, b0.y, b0.z, b0.w, b1.x, b1.y, b1.z};
      if (k >= A0 && k < A1) {
#pragma unroll
        for (int r = 0; r < 4; ++r) {
          acc1A[r] = fmaf(hv1.x, wa[r],     acc1A[r]);
          acc1A[r] = fmaf(hv1.y, wa[r + 1], acc1A[r]);
          acc1A[r] = fmaf(hv1.z, wa[r + 2], acc1A[r]);
          acc1A[r] = fmaf(hv1.w, wa[r + 3], acc1A[r]);
          acc1B[r] = fmaf(hv1.x, wb[r],     acc1B[r]);
          acc1B[r] = fmaf(hv1.y, wb[r + 1], acc1B[r]);
          acc1B[r] = fmaf(hv1.z, wb[r + 2], acc1B[r]);
          acc1B[r] = fmaf(hv1.w, wb[r + 3], acc1B[r]);
        }
      }
      if (k >= B0 && k < B1) {
#pragma unroll
        for (int r = 0; r < 4; ++r) {
          acc2A[r] = fmaf(hv2.x, wa[r],     acc2A[r]);
          acc2A[r] = fmaf(hv2.y, wa[r + 1], acc2A[r]);
          acc2A[r] = fmaf(hv2.z, wa[r + 2], acc2A[r]);
          acc2A[r] = fmaf(hv2.w, wa[r + 3], acc2A[r]);
          acc2B[r] = fmaf(hv2.x, wb[r],     acc2B[r]);
          acc2B[r] = fmaf(hv2.y, wb[r + 1], acc2B[r]);
          acc2B[r] = fmaf(hv2.z, wb[r + 2], acc2B[r]);
          acc2B[r] = fmaf(hv2.w, wb[r + 3], acc2B[r]);
        }
      }
      a0 = a1; a1 = a2;
      b0 = b1; b1 = b2;
      hv1 = hv1n; hv2 = hv2n;
    }
  }
  float* out1 = filt + ((size_t)n * NF + o1) * TT;
  float* out2 = filt + ((size_t)n * NF + o2) * TT;
  *(float4*)&out1[bA] = make_float4(acc1A[0], acc1A[1], acc1A[2], acc1A[3]);
  *(float4*)&out1[bB] = make_float4(acc1B[0], acc1B[1], acc1B[2], acc1B[3]);
  *(float4*)&out2[bA] = make_float4(acc2A[0], acc2A[1], acc2A[2], acc2A[3]);
  *(float4*)&out2[bB] = make_float4(acc2B[0], acc2B[1], acc2B[2], acc2B[3]);
}

// ---------------------------------------------------------------------------
// Kernel B: Hilbert for TWO real rows per block via one complex FFT.
//   w = IFFT(mask * FFT(x1 + i*x2)) = z1 + i*z2  (mask is linear)
//   Re(z)=x exactly  =>  h1 = Im(w) - x2,  h2 = x1 - Re(w)
// Forward DIF (natural -> bit-reversed) + true inverse DIT (bit-reversed ->
// natural); the Hilbert mask is applied IN BIT-REVERSED SPACE where it is a
// pure parity rule: pos 0,1 -> x1; even -> x2; odd>=3 -> 0.
// No bit-reversal pass at all (the old one was a 64-way bank conflict: for
// lanes 0..63 brev11(t) is a multiple of 32 -> all lanes hit bank 0).
// ---------------------------------------------------------------------------
__global__ __launch_bounds__(256) void hilbert_kernel(float* __restrict__ filt) {
  __shared__ float re[TT], im[TT];
  __shared__ float twr[TT], twi[TT];   // tw[half+j] = exp(-i*pi*j/half)
  const int tid = threadIdx.x;
  const int blk = blockIdx.x;          // rows 2*blk, 2*blk+1
  float* row1 = filt + (size_t)(2 * blk) * TT;
  float* row2 = row1 + TT;
  for (int i = tid; i < TT; i += 256) {
    if (i == 0) { twr[0] = 1.f; twi[0] = 0.f; }
    else {
      int half = 1 << (31 - __clz(i));
      int j = i - half;
      float ang = -3.14159265358979323846f * (float)j / (float)half;
      float s, c;
      sincosf(ang, &s, &c);
      twr[i] = c; twi[i] = s;
    }
    re[i] = row1[i];
    im[i] = row2[i];
  }
  __syncthreads();
  // ---- forward DIF: half = 1024 .. 1, output in bit-reversed order ----
  for (int half = 1024; half >= 1; half >>= 1) {
    for (int bf = tid; bf < 1024; bf += 256) {
      const int j = bf & (half - 1);
      const int i0 = ((bf & ~(half - 1)) << 1) + j;
      const int i1 = i0 + half;
      const float c = twr[half + j], s = twi[half + j];
      float ur = re[i0], ui = im[i0];
      float vr = re[i1], vi = im[i1];
      re[i0] = ur + vr; im[i0] = ui + vi;
      float dr = ur - vr, di = ui - vi;
      re[i1] = fmaf(c, dr, -(s * di));
      im[i1] = fmaf(c, di, s * dr);
    }
    __syncthreads();
  }
  // ---- Hilbert mask in bit-reversed space ----
  for (int jj = tid; jj < TT; jj += 256) {
    if (jj >= 2) {
      if (jj & 1) { re[jj] = 0.f; im[jj] = 0.f; }
      else        { re[jj] *= 2.f; im[jj] *= 2.f; }
    }
  }
  __syncthreads();
  // ---- inverse DIT: half = 1 .. 1024, bit-reversed in -> natural out ----
  for (int half = 1; half <= 1024; half <<= 1) {
    for (int bf = tid; bf < 1024; bf += 256) {
      const int j = bf & (half - 1);
      const int i0 = ((bf & ~(half - 1)) << 1) + j;
      const int i1 = i0 + half;
      const float c = twr[half + j], s = twi[half + j];  // use conj -> e^{+i}
      float vr = re[i1], vi = im[i1];
      float tr = fmaf(c, vr, s * vi);
      float ti = fmaf(c, vi, -(s * vr));
      float ur = re[i0], ui = im[i0];
      re[i0] = ur + tr; im[i0] = ui + ti;
      re[i1] = ur - tr; im[i1] = ui - ti;
    }
    __syncthreads();
  }
  // ---- recover h1,h2; write phase/amp ----
  const int o1 = (2 * blk) % NF;       // even -> pair never crosses pha/amp
  const bool p1 = o1 < 10, p2 = (o1 + 1) < 10;
  const float invN = 1.0f / 2048.0f;
  for (int t = tid; t < TT; t += 256) {
    float x1 = row1[t], x2 = row2[t];
    float wr = re[t] * invN, wi = im[t] * invN;
    float h1 = wi - x2;
    float h2 = x1 - wr;
    row1[t] = p1 ? atan2f(h1, x1) : sqrtf(fmaf(x1, x1, h1 * h1));
    row2[t] = p2 ? atan2f(h2, x2) : sqrtf(fmaf(x2, x2, h2 * h2));
  }
}

// ---------------------------------------------------------------------------
// Kernel C: binned MI with the reference's RESHAPE-SCRAMBLED pairing.
// (see round-2 notes). 320 threads: a = tid>>5 (amp band), sl = tid&31, so
// each 32-lane half-wave reads 128B contiguous from its amp row (coalesced).
// ---------------------------------------------------------------------------
__global__ __launch_bounds__(320) void mi_kernel(const float* __restrict__ filt,
                                                 float* __restrict__ mi) {
  __shared__ int idx[TT];
  __shared__ float bins[320 * 19];
  __shared__ float cnt[32 * 19];
  __shared__ float asum[10 * 19];
  __shared__ float csum[19];
  const int tid = threadIdx.x;
  const int blk = blockIdx.x;           // bc*40 + jp
  const int bc = blk / 40, jp = blk % 40;
  for (int i = tid; i < 320 * 19; i += 320) bins[i] = 0.f;
  for (int i = tid; i < 32 * 19; i += 320) cnt[i] = 0.f;
  const float* ph = filt + ((size_t)(bc * 4 + jp / 10) * NF + (jp % 10)) * TT;
  for (int t = tid; t < TT; t += 320) {
    float v = ph[t];
    int b = (int)floorf((v + 3.14159274f) / 6.2831855f * 18.0f);
    b = b < 0 ? 0 : (b > 17 ? 17 : b);
    idx[t] = b;
  }
  __syncthreads();
  {
    const int a = tid >> 5, sl = tid & 31;   // a = a' (output amp index)
    const int ja = (jp & 3) + 4 * a;         // scrambled amp row, same s'
    const float* am = filt + ((size_t)(bc * 4 + ja / 10) * NF + 10 + (ja % 10)) * TT;
    float* bp = &bins[tid * 19];
    if (a == 0) {
      float* cp = &cnt[sl * 19];
      for (int t = sl; t < TT; t += 32) {
        int b = idx[t];
        bp[b] += am[t];
        cp[b] += 1.f;
      }
    } else {
      for (int t = sl; t < TT; t += 32) {
        int b = idx[t];
        bp[b] += am[t];
      }
    }
  }
  __syncthreads();
  if (tid < 180) {
    const int a = tid / 18, b = tid % 18;
    float s = 0.f;
    for (int sl = 0; sl < 32; ++sl) s += bins[(a * 32 + sl) * 19 + b];
    asum[a * 19 + b] = s;
  }
  if (tid >= 192 && tid < 210) {
    const int b = tid - 192;
    float s = 0.f;
    for (int sl = 0; sl < 32; ++sl) s += cnt[sl * 19 + b];
    csum[b] = s;
  }
  __syncthreads();
  if (tid < 10) {
    float tot = 0.f, m[18];
#pragma unroll
    for (int b = 0; b < 18; ++b) {
      float mb = asum[tid * 19 + b] / fmaxf(csum[b], 1.0f);
      m[b] = mb; tot += mb;
    }
    tot = fmaxf(tot, 1e-12f);
    float s = 0.f;
#pragma unroll
    for (int b = 0; b < 18; ++b) {
      float pb = m[b] / tot;
      s += pb * logf(fmaxf(pb, 1e-12f));
    }
    const float LOGN = 2.8903717578961645f; // log(18)
    mi[(size_t)blk * 10 + tid] = (LOGN + s) / LOGN;
  }
}

// ---------------------------------------------------------------------------
// Kernel D: mean over the scrambled s' axis -> out (4,8,10,10)
// ---------------------------------------------------------------------------
__global__ void out_kernel(const float* __restrict__ mi, float* __restrict__ out) {
  int i = blockIdx.x * 256 + threadIdx.x;
  if (i < 3200) {
    int a = i % 10, p = (i / 10) % 10, bc = i / 100;
    float s = 0.f;
    for (int sp = 0; sp < 4; ++sp)
      s += mi[((size_t)(bc * 40 + p * 4 + sp)) * 10 + a];
    out[i] = 0.25f * s;
  }
}

extern "C" void kernel_launch(void* const* d_in, const int* in_sizes, int n_in,
                              void* d_out, int out_size, void* d_ws, size_t ws_size,
                              hipStream_t stream) {
  (void)in_sizes; (void)n_in; (void)out_size; (void)ws_size;
  const float* x = (const float*)d_in[0];     // (4,8,4,2048) fp32
  const float* ker = (const float*)d_in[1];   // (20,769) fp32
  float* out = (float*)d_out;                 // 3200 fp32
  float* filt = (float*)d_ws;                 // 128*20*2048 fp32 (~21 MB)
  float* mi = filt + (size_t)NS * NF * TT;    // 12800 fp32

  conv_kernel<<<NS * 10, 256, 0, stream>>>(x, ker, filt);
  hilbert_kernel<<<NS * NF / 2, 256, 0, stream>>>(filt);
  mi_kernel<<<32 * 40, 320, 0, stream>>>(filt, mi);
  out_kernel<<<(3200 + 255) / 256, 256, 0, stream>>>(mi, out);
}